// Round 4
// baseline (275.715 us; speedup 1.0000x reference)
//
#include <hip/hip_runtime.h>

// ---------------------------------------------------------------------------
// 2-layer GCN. R13: agg split into 4 SEQUENTIAL DIM-SLICE PASSES (64B each).
// Post-mortem R10 (211.8 vs 214.8): removing the cross-lane reduce + 75% of
// waves saved only 3us -> aggs are memory-bound on the gather, not on
// instructions. Budget puts ~160us in the two aggs (~80 each) = 1.8 TB/s
// effective on 205MB of random 64B-line traffic -> LLC request-rate bound
// (12.8MB table >> 4MB per-XCD L2, ~31% L2 hit).
// R13 theory: slice the 256B row into 4x64B sub-rows, one SEQUENTIAL kernel
// launch per slice. Per-pass line footprint = 50k x 64B = 3.2MB < 4MB L2
// (L2 caches lines; stride irrelevant to capacity) -> ~90% L2 hits, ~3x
// fewer LLC requests, ~3x lower latency per request. This is R8's goal with
// R8's failure modes repaired: R8 ran slices CONCURRENTLY in one grid
// (combined 12.8MB footprint thrashed -> 126MB HBM FETCH); sequential
// launches give temporal separation. No layout changes anywhere.
// Cost: +6 launches (~10us), 4x csr re-read (streamed, ~2us).
// Prediction: 212 -> ~130-160us if theory right; flat if aggs were already
// fast (then pivot to scatter/build).
// Structure:
//   scatter: packed (src|dst_low7<<16) into fixed per-bucket windows,
//            W fp16-transpose rides on spare blocks.
//   build:   per-bucket LDS degree/scan/fill -> rowstart/rowend/dinv/csr,
//            xs = fp16(x*dinv) fused.
//   q1 = fp16(dinv*(xs_self + sum xs[u]))   [agg32 x4 slices, sequential]
//   p2 = fp16(relu(q1@W1+b1)*dinv)          [MFMA gemm, fused epilogue]
//   q2 = fp16(dinv*(p2_self + sum p2[u]))   [agg32 x4 slices, sequential]
//   out = relu(q2@W2+b2) fp32               [MFMA gemm]
// ---------------------------------------------------------------------------

typedef __attribute__((ext_vector_type(8))) _Float16 half8;
typedef __attribute__((ext_vector_type(4))) _Float16 half4v;
typedef __attribute__((ext_vector_type(2))) _Float16 half2v;
typedef __attribute__((ext_vector_type(4))) float floatx4;

#define BSHIFT 7
#define BNODES 128       // nodes per bucket
#define BCAP   4096      // edge capacity per bucket (mean 2046, sigma ~45)

// ---- scatter packed (src | dst_low7<<16) into fixed bucket windows ---------
// Blocks [0,256): scatter. Blocks [256,448): W1/W2 fp32 -> fp16 transposed.
__global__ __launch_bounds__(256) void scatter_conv_kernel(const int* __restrict__ src,
                                                           const int* __restrict__ dst,
                                                           int* __restrict__ bucket_fill,
                                                           unsigned* __restrict__ bucketed,
                                                           const float* __restrict__ W1,
                                                           const float* __restrict__ W2,
                                                           _Float16* __restrict__ wt1,
                                                           _Float16* __restrict__ wt2,
                                                           int E, int chunk, int NB) {
    int t = threadIdx.x;
    if (blockIdx.x >= 256) {
        int idx = (blockIdx.x - 256) * 256 + t;
        if (idx < 128 * 128) {
            int nn = idx >> 7, k = idx & 127;
            wt1[idx] = (_Float16)W1[k * 128 + nn];
        } else if (idx < (128 + 256) * 128) {
            int j = idx - 128 * 128;
            int nn = j >> 7, k = j & 127;
            wt2[j] = (_Float16)W2[k * 256 + nn];
        }
        return;
    }
    extern __shared__ int sh[];       // hist | base_loc | cur2  (3*NB ints)
    int* hist = sh;
    int* base_loc = sh + NB;
    int* cur2 = sh + 2 * NB;
    for (int i = t; i < NB; i += 256) { hist[i] = 0; cur2[i] = 0; }
    __syncthreads();
    int cbeg = blockIdx.x * chunk;
    int cend = min(E, cbeg + chunk);
    for (int e = cbeg + t; e < cend; e += 256)
        atomicAdd(&hist[dst[e] >> BSHIFT], 1);
    __syncthreads();
    for (int i = t; i < NB; i += 256) {
        int c = hist[i];
        base_loc[i] = c ? atomicAdd(&bucket_fill[i], c) : 0;
    }
    __syncthreads();
    for (int e = cbeg + t; e < cend; e += 256) {
        int d = dst[e];
        int bkt = d >> BSHIFT;
        int r = atomicAdd(&cur2[bkt], 1);
        bucketed[(size_t)bkt * BCAP + base_loc[bkt] + r] =
            (unsigned)src[e] | ((unsigned)(d & (BNODES - 1)) << 16);
    }
}

// ---- per-bucket CSR build + dinv + xs conversion ---------------------------
__global__ __launch_bounds__(256) void build_kernel(const unsigned* __restrict__ bucketed,
                                                    const int* __restrict__ bucket_fill,
                                                    const float* __restrict__ x,
                                                    int* __restrict__ rowstart,
                                                    int* __restrict__ rowend,
                                                    float* __restrict__ dinv,
                                                    int* __restrict__ csr,
                                                    _Float16* __restrict__ xs,
                                                    int N, int NB) {
    __shared__ int deg_loc[BNODES];
    __shared__ int tmp[BNODES];
    __shared__ int cur_loc[BNODES];
    __shared__ float dinv_loc[BNODES];
    int t = threadIdx.x;
    int b = blockIdx.x;
    int n0 = b << BSHIFT;
    int nodes_in = min(BNODES, N - n0);
    size_t wbase = (size_t)b * BCAP;
    int cnt = bucket_fill[b];

    if (t < BNODES) deg_loc[t] = 0;
    __syncthreads();
    for (int e = t; e < cnt; e += 256)
        atomicAdd(&deg_loc[bucketed[wbase + e] >> 16], 1);
    __syncthreads();
    if (t < BNODES) tmp[t] = deg_loc[t];
    __syncthreads();
    for (int off = 1; off < BNODES; off <<= 1) {
        int v = 0;
        if (t < BNODES && t >= off) v = tmp[t - off];
        __syncthreads();
        if (t < BNODES) tmp[t] += v;
        __syncthreads();
    }
    if (t < BNODES) {
        int abs0 = (int)wbase + tmp[t] - deg_loc[t];
        cur_loc[t] = abs0;
        float dv = rsqrtf((float)(deg_loc[t] + 1));
        dinv_loc[t] = dv;
        if (t < nodes_in) {
            rowstart[n0 + t] = abs0;
            rowend[n0 + t] = abs0 + deg_loc[t];
            dinv[n0 + t] = dv;
        }
    }
    __syncthreads();
    for (int e = t; e < cnt; e += 256) {
        unsigned u2 = bucketed[wbase + e];
        int pos = atomicAdd(&cur_loc[u2 >> 16], 1);
        csr[pos] = (int)(u2 & 0xFFFFu);
    }
    // xs = fp16(x * dinv) for this bucket's rows (coalesced float4)
    int total4 = nodes_in * 32;  // 32 float4 per 128-wide row
    const float4* x4 = (const float4*)(x + (size_t)n0 * 128);
    for (int i = t; i < total4; i += 256) {
        int row = i >> 5;
        float dv = dinv_loc[row];
        float4 v = x4[i];
        half4v h;
        h[0] = (_Float16)(v.x * dv); h[1] = (_Float16)(v.y * dv);
        h[2] = (_Float16)(v.z * dv); h[3] = (_Float16)(v.w * dv);
        *(half4v*)(xs + (size_t)n0 * 128 + (size_t)i * 4) = h;
    }
}

// ---- 32-dim slice gather aggregation: node per quarter-wave, slice s -------
// Pass s computes out[v][32s..32s+32) = fp16(dinv[v]*(g[v]+sum g[u])) over
// the 64B sub-row. 16 lanes x 4B per edge; per-pass gather footprint is one
// 64B line per node = 3.2MB -> per-XCD-L2 resident. Launched 4x sequentially.
__global__ __launch_bounds__(256) void agg32_kernel(const _Float16* __restrict__ g,
                                                    const int* __restrict__ rowstart,
                                                    const int* __restrict__ rowend,
                                                    const float* __restrict__ dinv,
                                                    const int* __restrict__ csr,
                                                    _Float16* __restrict__ out,
                                                    int n, int s32) {
    int wave = (blockIdx.x * blockDim.x + threadIdx.x) >> 6;
    int lane = threadIdx.x & 63;
    int q = lane >> 4, l16 = lane & 15;
    int node = wave * 4 + q;
    if (node >= n) return;
    int beg = rowstart[node], end = rowend[node];
    const _Float16* gs = g + s32 + l16 * 2;   // slice+lane base

    float a0, a1;
    {   // self term
        half2v v = *(const half2v*)(gs + (size_t)node * 128);
        a0 = (float)v[0]; a1 = (float)v[1];
    }
    int e = beg;
    for (; e + 7 < end; e += 8) {   // 8 gathers in flight per quarter
        int u0 = csr[e],     u1 = csr[e + 1], u2 = csr[e + 2], u3 = csr[e + 3];
        int u4 = csr[e + 4], u5 = csr[e + 5], u6 = csr[e + 6], u7 = csr[e + 7];
        half2v v0 = *(const half2v*)(gs + (size_t)u0 * 128);
        half2v v1 = *(const half2v*)(gs + (size_t)u1 * 128);
        half2v v2 = *(const half2v*)(gs + (size_t)u2 * 128);
        half2v v3 = *(const half2v*)(gs + (size_t)u3 * 128);
        half2v v4 = *(const half2v*)(gs + (size_t)u4 * 128);
        half2v v5 = *(const half2v*)(gs + (size_t)u5 * 128);
        half2v v6 = *(const half2v*)(gs + (size_t)u6 * 128);
        half2v v7 = *(const half2v*)(gs + (size_t)u7 * 128);
        a0 += (((float)v0[0] + (float)v1[0]) + ((float)v2[0] + (float)v3[0])) +
              (((float)v4[0] + (float)v5[0]) + ((float)v6[0] + (float)v7[0]));
        a1 += (((float)v0[1] + (float)v1[1]) + ((float)v2[1] + (float)v3[1])) +
              (((float)v4[1] + (float)v5[1]) + ((float)v6[1] + (float)v7[1]));
    }
    for (; e + 3 < end; e += 4) {
        int u0 = csr[e], u1 = csr[e + 1], u2 = csr[e + 2], u3 = csr[e + 3];
        half2v v0 = *(const half2v*)(gs + (size_t)u0 * 128);
        half2v v1 = *(const half2v*)(gs + (size_t)u1 * 128);
        half2v v2 = *(const half2v*)(gs + (size_t)u2 * 128);
        half2v v3 = *(const half2v*)(gs + (size_t)u3 * 128);
        a0 += ((float)v0[0] + (float)v1[0]) + ((float)v2[0] + (float)v3[0]);
        a1 += ((float)v0[1] + (float)v1[1]) + ((float)v2[1] + (float)v3[1]);
    }
    for (; e < end; e++) {
        int u = csr[e];
        half2v v = *(const half2v*)(gs + (size_t)u * 128);
        a0 += (float)v[0]; a1 += (float)v[1];
    }
    float dv = dinv[node];
    half2v o;
    o[0] = (_Float16)(a0 * dv); o[1] = (_Float16)(a1 * dv);
    *(half2v*)(out + (size_t)node * 128 + s32 + l16 * 2) = o;
}

// ---- fp16 MFMA GEMM, K=128, BM=BN=128, fused epilogue ----------------------
// HALF_OUT: out = fp16(relu(acc+bias)*dinv)   else: fp32 relu(acc+bias)
// MFMA layouts (m89/m120): A[m=lane&15][k=(lane>>4)*8+j], B as Bt[n][k],
// D[row=(lane>>4)*4+reg][col=lane&15].
template <bool HALF_OUT>
__global__ __launch_bounds__(256) void gemm_kernel(const _Float16* __restrict__ A,   // [n][128]
                                                   const _Float16* __restrict__ Bt,  // [nout][128]
                                                   const float* __restrict__ bias,
                                                   const float* __restrict__ dinv,
                                                   void* __restrict__ outp,
                                                   int n, int nout) {
    __shared__ _Float16 As[128][136];
    __shared__ _Float16 Bs[128][136];
    int t = threadIdx.x;
    int row0 = blockIdx.x * 128;
    int col0 = blockIdx.y * 128;

#pragma unroll
    for (int i = 0; i < 8; i++) {
        int c = i * 256 + t;
        int r = c >> 4, seg = c & 15;
        int gr = row0 + r;
        if (gr >= n) gr = n - 1;  // clamp; extra rows never stored
        uint4 v = *(const uint4*)(A + (size_t)gr * 128 + seg * 8);
        *(uint4*)(&As[r][seg * 8]) = v;
    }
#pragma unroll
    for (int i = 0; i < 8; i++) {
        int c = i * 256 + t;
        int r = c >> 4, seg = c & 15;
        uint4 v = *(const uint4*)(Bt + (size_t)(col0 + r) * 128 + seg * 8);
        *(uint4*)(&Bs[r][seg * 8]) = v;
    }
    __syncthreads();

    int wid = t >> 6, lane = t & 63;
    int wm = wid >> 1, wn = wid & 1;
    int quad = lane >> 4, l16 = lane & 15;

    floatx4 acc[4][4];
#pragma unroll
    for (int mt = 0; mt < 4; mt++)
#pragma unroll
        for (int nt = 0; nt < 4; nt++) acc[mt][nt] = (floatx4){0.f, 0.f, 0.f, 0.f};

#pragma unroll
    for (int ks = 0; ks < 4; ks++) {
        int k0 = ks * 32 + quad * 8;
        half8 a[4], b[4];
#pragma unroll
        for (int mt = 0; mt < 4; mt++)
            a[mt] = *(const half8*)(&As[wm * 64 + mt * 16 + l16][k0]);
#pragma unroll
        for (int nt = 0; nt < 4; nt++)
            b[nt] = *(const half8*)(&Bs[wn * 64 + nt * 16 + l16][k0]);
#pragma unroll
        for (int mt = 0; mt < 4; mt++)
#pragma unroll
            for (int nt = 0; nt < 4; nt++)
                acc[mt][nt] = __builtin_amdgcn_mfma_f32_16x16x32_f16(a[mt], b[nt], acc[mt][nt], 0, 0, 0);
    }

#pragma unroll
    for (int mt = 0; mt < 4; mt++) {
        int rbase = row0 + wm * 64 + mt * 16 + quad * 4;
#pragma unroll
        for (int reg = 0; reg < 4; reg++) {
            int r = rbase + reg;
            if (r < n) {
                float dv = HALF_OUT ? dinv[r] : 1.f;
#pragma unroll
                for (int nt = 0; nt < 4; nt++) {
                    int cc = col0 + wn * 64 + nt * 16 + l16;
                    float val = fmaxf(acc[mt][nt][reg] + bias[cc], 0.f);
                    if (HALF_OUT)
                        ((_Float16*)outp)[(size_t)r * nout + cc] = (_Float16)(val * dv);
                    else
                        ((float*)outp)[(size_t)r * nout + cc] = val;
                }
            }
        }
    }
}

extern "C" void kernel_launch(void* const* d_in, const int* in_sizes, int n_in,
                              void* d_out, int out_size, void* d_ws, size_t ws_size,
                              hipStream_t stream) {
    const float* x  = (const float*)d_in[0];
    const int*   ei = (const int*)d_in[1];
    const float* W1 = (const float*)d_in[2];
    const float* b1 = (const float*)d_in[3];
    const float* W2 = (const float*)d_in[4];
    const float* b2 = (const float*)d_in[5];
    float* out = (float*)d_out;

    int N = in_sizes[0] / 128;   // 50000
    int E = in_sizes[1] / 2;     // 800000
    const int* src = ei;
    const int* dst = ei + E;
    int NB = (N + BNODES - 1) >> BSHIFT;   // 391 buckets

    char* w = (char*)d_ws;
    size_t off = 0;
    auto alloc = [&](size_t bytes) -> char* {
        char* p = w + off;
        off = (off + bytes + 255) & ~(size_t)255;
        return p;
    };
    int*      bucket_fill = (int*)alloc((size_t)NB * 4);
    unsigned* bucketed    = (unsigned*)alloc((size_t)NB * BCAP * 4);
    int*      rowstart    = (int*)alloc((size_t)N * 4);
    int*      rowend      = (int*)alloc((size_t)N * 4);
    float*    dinv        = (float*)alloc((size_t)N * 4);
    int*      csr         = (int*)alloc((size_t)NB * BCAP * 4);
    _Float16* wt1         = (_Float16*)alloc((size_t)128 * 128 * 2);
    _Float16* wt2         = (_Float16*)alloc((size_t)256 * 128 * 2);
    _Float16* xs          = (_Float16*)alloc((size_t)N * 128 * 2);
    _Float16* q1          = (_Float16*)alloc((size_t)N * 128 * 2);
    _Float16* p2          = (_Float16*)alloc((size_t)N * 128 * 2);
    _Float16* q2          = (_Float16*)alloc((size_t)N * 128 * 2);

    int chunk = (E + 255) / 256;          // edges per scatter block
    size_t lds3 = (size_t)NB * 12;        // scatter hist+base+cur

    hipMemsetAsync(bucket_fill, 0, (size_t)NB * 4, stream);
    hipLaunchKernelGGL(scatter_conv_kernel, dim3(256 + 192), dim3(256), lds3, stream,
                       src, dst, bucket_fill, bucketed, W1, W2, wt1, wt2, E, chunk, NB);
    hipLaunchKernelGGL(build_kernel, dim3(NB), dim3(256), 0, stream,
                       bucketed, bucket_fill, x, rowstart, rowend, dinv, csr, xs, N, NB);

    int gbm = (N + 127) / 128;            // 391
    int nwave = (N + 3) / 4;              // one node per quarter-wave
    int nb_agg = (nwave * 64 + 255) / 256;  // 3125 blocks
    // layer 1: 4 sequential dim-slice passes (each L2-resident)
    for (int s = 0; s < 4; s++)
        hipLaunchKernelGGL(agg32_kernel, dim3(nb_agg), dim3(256), 0, stream,
                           xs, rowstart, rowend, dinv, csr, q1, N, s * 32);
    hipLaunchKernelGGL((gemm_kernel<true>), dim3(gbm, 1), dim3(256), 0, stream, q1, wt1, b1, dinv, (void*)p2, N, 128);
    // layer 2
    for (int s = 0; s < 4; s++)
        hipLaunchKernelGGL(agg32_kernel, dim3(nb_agg), dim3(256), 0, stream,
                           p2, rowstart, rowend, dinv, csr, q2, N, s * 32);
    hipLaunchKernelGGL((gemm_kernel<false>), dim3(gbm, 2), dim3(256), 0, stream, q2, wt2, b2, dinv, (void*)out, N, 256);
}

// Round 5
// 251.698 us; speedup vs baseline: 1.0954x; 1.0954x over previous
//
#include <hip/hip_runtime.h>

// ---------------------------------------------------------------------------
// 2-layer GCN. R14: R10 agg structure + SRC-SORTED EDGE LISTS (sweep locality).
// Post-mortems:
//  R10 (212): removing cross-lane reduce + 75% of waves: -3us -> aggs not
//    instruction/latency bound (outstanding-request arithmetic shows 50x
//    over-provisioned concurrency) -> bound on random line-request service.
//  R13 (276): 4x dim-slice passes kept data-line count constant (3.2M/layer)
//    but 4x'd instructions/csr/launches -> -64us. Per-pass per-XCD reuse is
//    only E/N/XCD~2 -> max 50% hits; compulsory (XCD x pass x footprint)
//    unchanged. Slicing multiplies requests without concentrating reuse.
// R14 theory: sort each node's edge list by src. Waves advance in near-
// lockstep (deg 16+-4), so at progress f every concurrent wave gathers from
// src ~ f*50k +- small spread: a ~2-4MB band sweeping the 12.8MB table ->
// per-XCD-L2 resident -> repeat touches become L2 hits. Same request count,
// same instructions, same waves; only temporal address distribution changes.
// Sort done in LDS in build (cap-49 rows, perf-only property).
// Prediction: 212 -> 150-185 if tier-sensitive; flat if fixed request rate
// (then gather floor is structural -> XCD-partitioned partials or stop).
// Structure:
//   scatter: packed (src|dst_low7<<16) into fixed per-bucket windows,
//            W fp16-transpose rides on spare blocks.
//   build:   per-bucket LDS degree/scan/fill -> rowstart/rowend/dinv/csr,
//            per-row LDS insertion sort by src, xs = fp16(x*dinv) fused.
//   q1 = fp16(dinv*(xs_self + sum xs[u]))   [agg128: node-per-quarter]
//   p2 = fp16(relu(q1@W1+b1)*dinv)          [MFMA gemm, fused epilogue]
//   q2 = fp16(dinv*(p2_self + sum p2[u]))   [agg128]
//   out = relu(q2@W2+b2) fp32               [MFMA gemm]
// ---------------------------------------------------------------------------

typedef __attribute__((ext_vector_type(8))) _Float16 half8;
typedef __attribute__((ext_vector_type(4))) _Float16 half4v;
typedef __attribute__((ext_vector_type(4))) float floatx4;

#define BSHIFT 7
#define BNODES 128       // nodes per bucket
#define BCAP   4096      // edge capacity per bucket (mean 2046, sigma ~45)
#define SCAP   49        // per-row sort buffer (Poisson(16) max ~40; 49 = bank-spread pad)

// ---- scatter packed (src | dst_low7<<16) into fixed bucket windows ---------
// Blocks [0,256): scatter. Blocks [256,448): W1/W2 fp32 -> fp16 transposed.
__global__ __launch_bounds__(256) void scatter_conv_kernel(const int* __restrict__ src,
                                                           const int* __restrict__ dst,
                                                           int* __restrict__ bucket_fill,
                                                           unsigned* __restrict__ bucketed,
                                                           const float* __restrict__ W1,
                                                           const float* __restrict__ W2,
                                                           _Float16* __restrict__ wt1,
                                                           _Float16* __restrict__ wt2,
                                                           int E, int chunk, int NB) {
    int t = threadIdx.x;
    if (blockIdx.x >= 256) {
        int idx = (blockIdx.x - 256) * 256 + t;
        if (idx < 128 * 128) {
            int nn = idx >> 7, k = idx & 127;
            wt1[idx] = (_Float16)W1[k * 128 + nn];
        } else if (idx < (128 + 256) * 128) {
            int j = idx - 128 * 128;
            int nn = j >> 7, k = j & 127;
            wt2[j] = (_Float16)W2[k * 256 + nn];
        }
        return;
    }
    extern __shared__ int sh[];       // hist | base_loc | cur2  (3*NB ints)
    int* hist = sh;
    int* base_loc = sh + NB;
    int* cur2 = sh + 2 * NB;
    for (int i = t; i < NB; i += 256) { hist[i] = 0; cur2[i] = 0; }
    __syncthreads();
    int cbeg = blockIdx.x * chunk;
    int cend = min(E, cbeg + chunk);
    for (int e = cbeg + t; e < cend; e += 256)
        atomicAdd(&hist[dst[e] >> BSHIFT], 1);
    __syncthreads();
    for (int i = t; i < NB; i += 256) {
        int c = hist[i];
        base_loc[i] = c ? atomicAdd(&bucket_fill[i], c) : 0;
    }
    __syncthreads();
    for (int e = cbeg + t; e < cend; e += 256) {
        int d = dst[e];
        int bkt = d >> BSHIFT;
        int r = atomicAdd(&cur2[bkt], 1);
        bucketed[(size_t)bkt * BCAP + base_loc[bkt] + r] =
            (unsigned)src[e] | ((unsigned)(d & (BNODES - 1)) << 16);
    }
}

// ---- per-bucket CSR build + per-row src-sort + dinv + xs conversion --------
__global__ __launch_bounds__(256) void build_kernel(const unsigned* __restrict__ bucketed,
                                                    const int* __restrict__ bucket_fill,
                                                    const float* __restrict__ x,
                                                    int* __restrict__ rowstart,
                                                    int* __restrict__ rowend,
                                                    float* __restrict__ dinv,
                                                    int* __restrict__ csr,
                                                    _Float16* __restrict__ xs,
                                                    int N, int NB) {
    __shared__ int deg_loc[BNODES];
    __shared__ int tmp[BNODES];
    __shared__ int cur_loc[BNODES];
    __shared__ float dinv_loc[BNODES];
    __shared__ int srt[BNODES * SCAP];   // per-row sort scratch (25.1 KB)
    int t = threadIdx.x;
    int b = blockIdx.x;
    int n0 = b << BSHIFT;
    int nodes_in = min(BNODES, N - n0);
    size_t wbase = (size_t)b * BCAP;
    int cnt = bucket_fill[b];

    if (t < BNODES) deg_loc[t] = 0;
    __syncthreads();
    for (int e = t; e < cnt; e += 256)
        atomicAdd(&deg_loc[bucketed[wbase + e] >> 16], 1);
    __syncthreads();
    if (t < BNODES) tmp[t] = deg_loc[t];
    __syncthreads();
    for (int off = 1; off < BNODES; off <<= 1) {
        int v = 0;
        if (t < BNODES && t >= off) v = tmp[t - off];
        __syncthreads();
        if (t < BNODES) tmp[t] += v;
        __syncthreads();
    }
    if (t < BNODES) {
        int abs0 = (int)wbase + tmp[t] - deg_loc[t];
        cur_loc[t] = abs0;
        float dv = rsqrtf((float)(deg_loc[t] + 1));
        dinv_loc[t] = dv;
        if (t < nodes_in) {
            rowstart[n0 + t] = abs0;
            rowend[n0 + t] = abs0 + deg_loc[t];
            dinv[n0 + t] = dv;
        }
    }
    __syncthreads();
    for (int e = t; e < cnt; e += 256) {
        unsigned u2 = bucketed[wbase + e];
        int pos = atomicAdd(&cur_loc[u2 >> 16], 1);
        csr[pos] = (int)(u2 & 0xFFFFu);
    }
    __syncthreads();   // all csr writes for this bucket visible
    // sort each row's segment by src (LDS insertion sort; perf-only property:
    // gives the agg sweep its locality band. cap SCAP ~ never exceeded).
    if (t < nodes_in) {
        int deg = deg_loc[t];
        if (deg > 1 && deg <= SCAP) {
            int rb = (int)wbase + tmp[t] - deg;
            int* buf = &srt[t * SCAP];
            for (int i = 0; i < deg; i++) buf[i] = csr[rb + i];
            for (int i = 1; i < deg; i++) {
                int key = buf[i];
                int j = i - 1;
                while (j >= 0 && buf[j] > key) { buf[j + 1] = buf[j]; j--; }
                buf[j + 1] = key;
            }
            for (int i = 0; i < deg; i++) csr[rb + i] = buf[i];
        }
    }
    // xs = fp16(x * dinv) for this bucket's rows (coalesced float4)
    int total4 = nodes_in * 32;  // 32 float4 per 128-wide row
    const float4* x4 = (const float4*)(x + (size_t)n0 * 128);
    for (int i = t; i < total4; i += 256) {
        int row = i >> 5;
        float dv = dinv_loc[row];
        float4 v = x4[i];
        half4v h;
        h[0] = (_Float16)(v.x * dv); h[1] = (_Float16)(v.y * dv);
        h[2] = (_Float16)(v.z * dv); h[3] = (_Float16)(v.w * dv);
        *(half4v*)(xs + (size_t)n0 * 128 + (size_t)i * 4) = h;
    }
}

// ---- 128-dim gather aggregation: ONE NODE PER QUARTER-WAVE -----------------
// q[v] = fp16( dinv[v] * (g[v] + sum_{u->v} g[u]) ); g rows = 256B fp16.
// Edge lists are src-sorted: concurrent waves sweep the table in a compact
// band. 8/4-deep unroll keeps 16-32 gathers in flight per wave.
__global__ __launch_bounds__(256) void agg128_kernel(const _Float16* __restrict__ g,
                                                     const int* __restrict__ rowstart,
                                                     const int* __restrict__ rowend,
                                                     const float* __restrict__ dinv,
                                                     const int* __restrict__ csr,
                                                     _Float16* __restrict__ out, int n) {
    int wave = (blockIdx.x * blockDim.x + threadIdx.x) >> 6;
    int lane = threadIdx.x & 63;
    int q = lane >> 4, l16 = lane & 15;
    int node = wave * 4 + q;
    if (node >= n) return;
    int beg = rowstart[node], end = rowend[node];

    float a[8];
    {   // self term (all lanes active)
        half8 v = *(const half8*)(g + (size_t)node * 128 + l16 * 8);
#pragma unroll
        for (int j = 0; j < 8; j++) a[j] = (float)v[j];
    }
    int e = beg;
    for (; e + 7 < end; e += 8) {   // 8 rows in flight per quarter
        int u0 = csr[e],     u1 = csr[e + 1], u2 = csr[e + 2], u3 = csr[e + 3];
        int u4 = csr[e + 4], u5 = csr[e + 5], u6 = csr[e + 6], u7 = csr[e + 7];
        half8 v0 = *(const half8*)(g + (size_t)u0 * 128 + l16 * 8);
        half8 v1 = *(const half8*)(g + (size_t)u1 * 128 + l16 * 8);
        half8 v2 = *(const half8*)(g + (size_t)u2 * 128 + l16 * 8);
        half8 v3 = *(const half8*)(g + (size_t)u3 * 128 + l16 * 8);
        half8 v4 = *(const half8*)(g + (size_t)u4 * 128 + l16 * 8);
        half8 v5 = *(const half8*)(g + (size_t)u5 * 128 + l16 * 8);
        half8 v6 = *(const half8*)(g + (size_t)u6 * 128 + l16 * 8);
        half8 v7 = *(const half8*)(g + (size_t)u7 * 128 + l16 * 8);
#pragma unroll
        for (int j = 0; j < 8; j++)
            a[j] += (((float)v0[j] + (float)v1[j]) + ((float)v2[j] + (float)v3[j])) +
                    (((float)v4[j] + (float)v5[j]) + ((float)v6[j] + (float)v7[j]));
    }
    for (; e + 3 < end; e += 4) {   // 4 rows in flight
        int u0 = csr[e], u1 = csr[e + 1], u2 = csr[e + 2], u3 = csr[e + 3];
        half8 v0 = *(const half8*)(g + (size_t)u0 * 128 + l16 * 8);
        half8 v1 = *(const half8*)(g + (size_t)u1 * 128 + l16 * 8);
        half8 v2 = *(const half8*)(g + (size_t)u2 * 128 + l16 * 8);
        half8 v3 = *(const half8*)(g + (size_t)u3 * 128 + l16 * 8);
#pragma unroll
        for (int j = 0; j < 8; j++)
            a[j] += ((float)v0[j] + (float)v1[j]) + ((float)v2[j] + (float)v3[j]);
    }
    for (; e < end; e++) {
        int u = csr[e];
        half8 v = *(const half8*)(g + (size_t)u * 128 + l16 * 8);
#pragma unroll
        for (int j = 0; j < 8; j++) a[j] += (float)v[j];
    }
    float dv = dinv[node];
    half8 o;
#pragma unroll
    for (int j = 0; j < 8; j++) o[j] = (_Float16)(a[j] * dv);
    *(half8*)(out + (size_t)node * 128 + l16 * 8) = o;
}

// ---- fp16 MFMA GEMM, K=128, BM=BN=128, fused epilogue ----------------------
// HALF_OUT: out = fp16(relu(acc+bias)*dinv)   else: fp32 relu(acc+bias)
// MFMA layouts (m89/m120): A[m=lane&15][k=(lane>>4)*8+j], B as Bt[n][k],
// D[row=(lane>>4)*4+reg][col=lane&15].
template <bool HALF_OUT>
__global__ __launch_bounds__(256) void gemm_kernel(const _Float16* __restrict__ A,   // [n][128]
                                                   const _Float16* __restrict__ Bt,  // [nout][128]
                                                   const float* __restrict__ bias,
                                                   const float* __restrict__ dinv,
                                                   void* __restrict__ outp,
                                                   int n, int nout) {
    __shared__ _Float16 As[128][136];
    __shared__ _Float16 Bs[128][136];
    int t = threadIdx.x;
    int row0 = blockIdx.x * 128;
    int col0 = blockIdx.y * 128;

#pragma unroll
    for (int i = 0; i < 8; i++) {
        int c = i * 256 + t;
        int r = c >> 4, seg = c & 15;
        int gr = row0 + r;
        if (gr >= n) gr = n - 1;  // clamp; extra rows never stored
        uint4 v = *(const uint4*)(A + (size_t)gr * 128 + seg * 8);
        *(uint4*)(&As[r][seg * 8]) = v;
    }
#pragma unroll
    for (int i = 0; i < 8; i++) {
        int c = i * 256 + t;
        int r = c >> 4, seg = c & 15;
        uint4 v = *(const uint4*)(Bt + (size_t)(col0 + r) * 128 + seg * 8);
        *(uint4*)(&Bs[r][seg * 8]) = v;
    }
    __syncthreads();

    int wid = t >> 6, lane = t & 63;
    int wm = wid >> 1, wn = wid & 1;
    int quad = lane >> 4, l16 = lane & 15;

    floatx4 acc[4][4];
#pragma unroll
    for (int mt = 0; mt < 4; mt++)
#pragma unroll
        for (int nt = 0; nt < 4; nt++) acc[mt][nt] = (floatx4){0.f, 0.f, 0.f, 0.f};

#pragma unroll
    for (int ks = 0; ks < 4; ks++) {
        int k0 = ks * 32 + quad * 8;
        half8 a[4], b[4];
#pragma unroll
        for (int mt = 0; mt < 4; mt++)
            a[mt] = *(const half8*)(&As[wm * 64 + mt * 16 + l16][k0]);
#pragma unroll
        for (int nt = 0; nt < 4; nt++)
            b[nt] = *(const half8*)(&Bs[wn * 64 + nt * 16 + l16][k0]);
#pragma unroll
        for (int mt = 0; mt < 4; mt++)
#pragma unroll
            for (int nt = 0; nt < 4; nt++)
                acc[mt][nt] = __builtin_amdgcn_mfma_f32_16x16x32_f16(a[mt], b[nt], acc[mt][nt], 0, 0, 0);
    }

#pragma unroll
    for (int mt = 0; mt < 4; mt++) {
        int rbase = row0 + wm * 64 + mt * 16 + quad * 4;
#pragma unroll
        for (int reg = 0; reg < 4; reg++) {
            int r = rbase + reg;
            if (r < n) {
                float dv = HALF_OUT ? dinv[r] : 1.f;
#pragma unroll
                for (int nt = 0; nt < 4; nt++) {
                    int cc = col0 + wn * 64 + nt * 16 + l16;
                    float val = fmaxf(acc[mt][nt][reg] + bias[cc], 0.f);
                    if (HALF_OUT)
                        ((_Float16*)outp)[(size_t)r * nout + cc] = (_Float16)(val * dv);
                    else
                        ((float*)outp)[(size_t)r * nout + cc] = val;
                }
            }
        }
    }
}

extern "C" void kernel_launch(void* const* d_in, const int* in_sizes, int n_in,
                              void* d_out, int out_size, void* d_ws, size_t ws_size,
                              hipStream_t stream) {
    const float* x  = (const float*)d_in[0];
    const int*   ei = (const int*)d_in[1];
    const float* W1 = (const float*)d_in[2];
    const float* b1 = (const float*)d_in[3];
    const float* W2 = (const float*)d_in[4];
    const float* b2 = (const float*)d_in[5];
    float* out = (float*)d_out;

    int N = in_sizes[0] / 128;   // 50000
    int E = in_sizes[1] / 2;     // 800000
    const int* src = ei;
    const int* dst = ei + E;
    int NB = (N + BNODES - 1) >> BSHIFT;   // 391 buckets

    char* w = (char*)d_ws;
    size_t off = 0;
    auto alloc = [&](size_t bytes) -> char* {
        char* p = w + off;
        off = (off + bytes + 255) & ~(size_t)255;
        return p;
    };
    int*      bucket_fill = (int*)alloc((size_t)NB * 4);
    unsigned* bucketed    = (unsigned*)alloc((size_t)NB * BCAP * 4);
    int*      rowstart    = (int*)alloc((size_t)N * 4);
    int*      rowend      = (int*)alloc((size_t)N * 4);
    float*    dinv        = (float*)alloc((size_t)N * 4);
    int*      csr         = (int*)alloc((size_t)NB * BCAP * 4);
    _Float16* wt1         = (_Float16*)alloc((size_t)128 * 128 * 2);
    _Float16* wt2         = (_Float16*)alloc((size_t)256 * 128 * 2);
    _Float16* xs          = (_Float16*)alloc((size_t)N * 128 * 2);
    _Float16* q1          = (_Float16*)alloc((size_t)N * 128 * 2);
    _Float16* p2          = (_Float16*)alloc((size_t)N * 128 * 2);
    _Float16* q2          = (_Float16*)alloc((size_t)N * 128 * 2);

    int chunk = (E + 255) / 256;          // edges per scatter block
    size_t lds3 = (size_t)NB * 12;        // scatter hist+base+cur

    hipMemsetAsync(bucket_fill, 0, (size_t)NB * 4, stream);
    hipLaunchKernelGGL(scatter_conv_kernel, dim3(256 + 192), dim3(256), lds3, stream,
                       src, dst, bucket_fill, bucketed, W1, W2, wt1, wt2, E, chunk, NB);
    hipLaunchKernelGGL(build_kernel, dim3(NB), dim3(256), 0, stream,
                       bucketed, bucket_fill, x, rowstart, rowend, dinv, csr, xs, N, NB);

    int gbm = (N + 127) / 128;            // 391
    int nwave = (N + 3) / 4;              // one node per quarter-wave
    int nb_agg = (nwave * 64 + 255) / 256;  // 3125 blocks
    // layer 1
    hipLaunchKernelGGL(agg128_kernel, dim3(nb_agg), dim3(256), 0, stream, xs, rowstart, rowend, dinv, csr, q1, N);
    hipLaunchKernelGGL((gemm_kernel<true>), dim3(gbm, 1), dim3(256), 0, stream, q1, wt1, b1, dinv, (void*)p2, N, 128);
    // layer 2
    hipLaunchKernelGGL(agg128_kernel, dim3(nb_agg), dim3(256), 0, stream, p2, rowstart, rowend, dinv, csr, q2, N);
    hipLaunchKernelGGL((gemm_kernel<false>), dim3(gbm, 2), dim3(256), 0, stream, q2, wt2, b2, dinv, (void*)out, N, 256);
}

// Round 6
// 245.656 us; speedup vs baseline: 1.1224x; 1.0246x over previous
//
#include <hip/hip_runtime.h>

// ---------------------------------------------------------------------------
// 2-layer GCN. R15 = R14 with the per-row src-sort moved ENTIRELY INTO LDS.
// Post-mortems:
//  R10 (212): agg not instruction/latency bound -> bound on random line
//    request service (LLC tier).
//  R13 (276): dim-slice passes: per-XCD reuse = deg/8 ~ 2 regardless of
//    partition size -> slicing multiplies requests without adding reuse.
//  R14 (252): src-sorted rows DID help aggs (-15us band-sweep gain) but the
//    sort implementation cost +55us: per-int GLOBAL csr reads/writes in a
//    serial divergent loop (build: 497 GB/s, VALU 3.7%, occ 8%).
// R15: atomic row-fill into an LDS csr buffer (8KB), insertion-sort rows in
// LDS, write back to global coalesced. Keeps the agg gain, kills the sort
// cost. No other changes.
// Prediction: build 67->14-18us, total ~198-205us (new best). If aggs revert
// (~210+), band gain was noise -> structural LLC floor; then decide on the
// XCD-pinned fp16-partial scheme or declare.
// Structure:
//   scatter: packed (src|dst_low7<<16) into fixed per-bucket windows,
//            W fp16-transpose rides on spare blocks.
//   build:   per-bucket LDS degree/scan/fill(LDS)/sort(LDS)/coalesced-write
//            -> rowstart/rowend/dinv/csr, xs = fp16(x*dinv) fused.
//   q1 = fp16(dinv*(xs_self + sum xs[u]))   [agg128: node-per-quarter]
//   p2 = fp16(relu(q1@W1+b1)*dinv)          [MFMA gemm, fused epilogue]
//   q2 = fp16(dinv*(p2_self + sum p2[u]))   [agg128]
//   out = relu(q2@W2+b2) fp32               [MFMA gemm]
// ---------------------------------------------------------------------------

typedef __attribute__((ext_vector_type(8))) _Float16 half8;
typedef __attribute__((ext_vector_type(4))) _Float16 half4v;
typedef __attribute__((ext_vector_type(4))) float floatx4;

#define BSHIFT 7
#define BNODES 128       // nodes per bucket
#define BCAP   4096      // edge capacity per bucket (mean 2046, sigma ~45)

// ---- scatter packed (src | dst_low7<<16) into fixed bucket windows ---------
// Blocks [0,256): scatter. Blocks [256,448): W1/W2 fp32 -> fp16 transposed.
__global__ __launch_bounds__(256) void scatter_conv_kernel(const int* __restrict__ src,
                                                           const int* __restrict__ dst,
                                                           int* __restrict__ bucket_fill,
                                                           unsigned* __restrict__ bucketed,
                                                           const float* __restrict__ W1,
                                                           const float* __restrict__ W2,
                                                           _Float16* __restrict__ wt1,
                                                           _Float16* __restrict__ wt2,
                                                           int E, int chunk, int NB) {
    int t = threadIdx.x;
    if (blockIdx.x >= 256) {
        int idx = (blockIdx.x - 256) * 256 + t;
        if (idx < 128 * 128) {
            int nn = idx >> 7, k = idx & 127;
            wt1[idx] = (_Float16)W1[k * 128 + nn];
        } else if (idx < (128 + 256) * 128) {
            int j = idx - 128 * 128;
            int nn = j >> 7, k = j & 127;
            wt2[j] = (_Float16)W2[k * 256 + nn];
        }
        return;
    }
    extern __shared__ int sh[];       // hist | base_loc | cur2  (3*NB ints)
    int* hist = sh;
    int* base_loc = sh + NB;
    int* cur2 = sh + 2 * NB;
    for (int i = t; i < NB; i += 256) { hist[i] = 0; cur2[i] = 0; }
    __syncthreads();
    int cbeg = blockIdx.x * chunk;
    int cend = min(E, cbeg + chunk);
    for (int e = cbeg + t; e < cend; e += 256)
        atomicAdd(&hist[dst[e] >> BSHIFT], 1);
    __syncthreads();
    for (int i = t; i < NB; i += 256) {
        int c = hist[i];
        base_loc[i] = c ? atomicAdd(&bucket_fill[i], c) : 0;
    }
    __syncthreads();
    for (int e = cbeg + t; e < cend; e += 256) {
        int d = dst[e];
        int bkt = d >> BSHIFT;
        int r = atomicAdd(&cur2[bkt], 1);
        bucketed[(size_t)bkt * BCAP + base_loc[bkt] + r] =
            (unsigned)src[e] | ((unsigned)(d & (BNODES - 1)) << 16);
    }
}

// ---- per-bucket CSR build (fill+sort in LDS) + dinv + xs conversion --------
__global__ __launch_bounds__(256) void build_kernel(const unsigned* __restrict__ bucketed,
                                                    const int* __restrict__ bucket_fill,
                                                    const float* __restrict__ x,
                                                    int* __restrict__ rowstart,
                                                    int* __restrict__ rowend,
                                                    float* __restrict__ dinv,
                                                    int* __restrict__ csr,
                                                    _Float16* __restrict__ xs,
                                                    int N, int NB) {
    __shared__ int deg_loc[BNODES];
    __shared__ int tmp[BNODES];
    __shared__ int cur_loc[BNODES];
    __shared__ float dinv_loc[BNODES];
    __shared__ int lcsr[BCAP];        // 16 KB: whole bucket's csr in LDS
    int t = threadIdx.x;
    int b = blockIdx.x;
    int n0 = b << BSHIFT;
    int nodes_in = min(BNODES, N - n0);
    size_t wbase = (size_t)b * BCAP;
    int cnt = bucket_fill[b];

    if (t < BNODES) deg_loc[t] = 0;
    __syncthreads();
    for (int e = t; e < cnt; e += 256)
        atomicAdd(&deg_loc[bucketed[wbase + e] >> 16], 1);
    __syncthreads();
    if (t < BNODES) tmp[t] = deg_loc[t];
    __syncthreads();
    for (int off = 1; off < BNODES; off <<= 1) {
        int v = 0;
        if (t < BNODES && t >= off) v = tmp[t - off];
        __syncthreads();
        if (t < BNODES) tmp[t] += v;
        __syncthreads();
    }
    if (t < BNODES) {
        int loc0 = tmp[t] - deg_loc[t];        // LOCAL (in-bucket) row base
        cur_loc[t] = loc0;
        float dv = rsqrtf((float)(deg_loc[t] + 1));
        dinv_loc[t] = dv;
        if (t < nodes_in) {
            rowstart[n0 + t] = (int)wbase + loc0;
            rowend[n0 + t] = (int)wbase + loc0 + deg_loc[t];
            dinv[n0 + t] = dv;
        }
    }
    __syncthreads();
    // fill rows in LDS (scatter is LDS-fast; order within row arbitrary)
    for (int e = t; e < cnt; e += 256) {
        unsigned u2 = bucketed[wbase + e];
        int pos = atomicAdd(&cur_loc[u2 >> 16], 1);
        lcsr[pos] = (int)(u2 & 0xFFFFu);
    }
    __syncthreads();
    // per-row insertion sort by src, entirely in LDS (perf-only property:
    // gives the agg sweep its locality band)
    if (t < nodes_in) {
        int deg = deg_loc[t];
        int rb = tmp[t] - deg;
        for (int i = 1; i < deg; i++) {
            int key = lcsr[rb + i];
            int j = i - 1;
            while (j >= 0 && lcsr[rb + j] > key) { lcsr[rb + j + 1] = lcsr[rb + j]; j--; }
            lcsr[rb + j + 1] = key;
        }
    }
    __syncthreads();
    // coalesced writeback of the sorted bucket csr
    for (int e = t; e < cnt; e += 256)
        csr[wbase + e] = lcsr[e];
    // xs = fp16(x * dinv) for this bucket's rows (coalesced float4)
    int total4 = nodes_in * 32;  // 32 float4 per 128-wide row
    const float4* x4 = (const float4*)(x + (size_t)n0 * 128);
    for (int i = t; i < total4; i += 256) {
        int row = i >> 5;
        float dv = dinv_loc[row];
        float4 v = x4[i];
        half4v h;
        h[0] = (_Float16)(v.x * dv); h[1] = (_Float16)(v.y * dv);
        h[2] = (_Float16)(v.z * dv); h[3] = (_Float16)(v.w * dv);
        *(half4v*)(xs + (size_t)n0 * 128 + (size_t)i * 4) = h;
    }
}

// ---- 128-dim gather aggregation: ONE NODE PER QUARTER-WAVE -----------------
// q[v] = fp16( dinv[v] * (g[v] + sum_{u->v} g[u]) ); g rows = 256B fp16.
// Edge lists are src-sorted: concurrent waves sweep the table in a compact
// band. 8/4-deep unroll keeps 16-32 gathers in flight per wave.
__global__ __launch_bounds__(256) void agg128_kernel(const _Float16* __restrict__ g,
                                                     const int* __restrict__ rowstart,
                                                     const int* __restrict__ rowend,
                                                     const float* __restrict__ dinv,
                                                     const int* __restrict__ csr,
                                                     _Float16* __restrict__ out, int n) {
    int wave = (blockIdx.x * blockDim.x + threadIdx.x) >> 6;
    int lane = threadIdx.x & 63;
    int q = lane >> 4, l16 = lane & 15;
    int node = wave * 4 + q;
    if (node >= n) return;
    int beg = rowstart[node], end = rowend[node];

    float a[8];
    {   // self term (all lanes active)
        half8 v = *(const half8*)(g + (size_t)node * 128 + l16 * 8);
#pragma unroll
        for (int j = 0; j < 8; j++) a[j] = (float)v[j];
    }
    int e = beg;
    for (; e + 7 < end; e += 8) {   // 8 rows in flight per quarter
        int u0 = csr[e],     u1 = csr[e + 1], u2 = csr[e + 2], u3 = csr[e + 3];
        int u4 = csr[e + 4], u5 = csr[e + 5], u6 = csr[e + 6], u7 = csr[e + 7];
        half8 v0 = *(const half8*)(g + (size_t)u0 * 128 + l16 * 8);
        half8 v1 = *(const half8*)(g + (size_t)u1 * 128 + l16 * 8);
        half8 v2 = *(const half8*)(g + (size_t)u2 * 128 + l16 * 8);
        half8 v3 = *(const half8*)(g + (size_t)u3 * 128 + l16 * 8);
        half8 v4 = *(const half8*)(g + (size_t)u4 * 128 + l16 * 8);
        half8 v5 = *(const half8*)(g + (size_t)u5 * 128 + l16 * 8);
        half8 v6 = *(const half8*)(g + (size_t)u6 * 128 + l16 * 8);
        half8 v7 = *(const half8*)(g + (size_t)u7 * 128 + l16 * 8);
#pragma unroll
        for (int j = 0; j < 8; j++)
            a[j] += (((float)v0[j] + (float)v1[j]) + ((float)v2[j] + (float)v3[j])) +
                    (((float)v4[j] + (float)v5[j]) + ((float)v6[j] + (float)v7[j]));
    }
    for (; e + 3 < end; e += 4) {   // 4 rows in flight
        int u0 = csr[e], u1 = csr[e + 1], u2 = csr[e + 2], u3 = csr[e + 3];
        half8 v0 = *(const half8*)(g + (size_t)u0 * 128 + l16 * 8);
        half8 v1 = *(const half8*)(g + (size_t)u1 * 128 + l16 * 8);
        half8 v2 = *(const half8*)(g + (size_t)u2 * 128 + l16 * 8);
        half8 v3 = *(const half8*)(g + (size_t)u3 * 128 + l16 * 8);
#pragma unroll
        for (int j = 0; j < 8; j++)
            a[j] += ((float)v0[j] + (float)v1[j]) + ((float)v2[j] + (float)v3[j]);
    }
    for (; e < end; e++) {
        int u = csr[e];
        half8 v = *(const half8*)(g + (size_t)u * 128 + l16 * 8);
#pragma unroll
        for (int j = 0; j < 8; j++) a[j] += (float)v[j];
    }
    float dv = dinv[node];
    half8 o;
#pragma unroll
    for (int j = 0; j < 8; j++) o[j] = (_Float16)(a[j] * dv);
    *(half8*)(out + (size_t)node * 128 + l16 * 8) = o;
}

// ---- fp16 MFMA GEMM, K=128, BM=BN=128, fused epilogue ----------------------
// HALF_OUT: out = fp16(relu(acc+bias)*dinv)   else: fp32 relu(acc+bias)
// MFMA layouts (m89/m120): A[m=lane&15][k=(lane>>4)*8+j], B as Bt[n][k],
// D[row=(lane>>4)*4+reg][col=lane&15].
template <bool HALF_OUT>
__global__ __launch_bounds__(256) void gemm_kernel(const _Float16* __restrict__ A,   // [n][128]
                                                   const _Float16* __restrict__ Bt,  // [nout][128]
                                                   const float* __restrict__ bias,
                                                   const float* __restrict__ dinv,
                                                   void* __restrict__ outp,
                                                   int n, int nout) {
    __shared__ _Float16 As[128][136];
    __shared__ _Float16 Bs[128][136];
    int t = threadIdx.x;
    int row0 = blockIdx.x * 128;
    int col0 = blockIdx.y * 128;

#pragma unroll
    for (int i = 0; i < 8; i++) {
        int c = i * 256 + t;
        int r = c >> 4, seg = c & 15;
        int gr = row0 + r;
        if (gr >= n) gr = n - 1;  // clamp; extra rows never stored
        uint4 v = *(const uint4*)(A + (size_t)gr * 128 + seg * 8);
        *(uint4*)(&As[r][seg * 8]) = v;
    }
#pragma unroll
    for (int i = 0; i < 8; i++) {
        int c = i * 256 + t;
        int r = c >> 4, seg = c & 15;
        uint4 v = *(const uint4*)(Bt + (size_t)(col0 + r) * 128 + seg * 8);
        *(uint4*)(&Bs[r][seg * 8]) = v;
    }
    __syncthreads();

    int wid = t >> 6, lane = t & 63;
    int wm = wid >> 1, wn = wid & 1;
    int quad = lane >> 4, l16 = lane & 15;

    floatx4 acc[4][4];
#pragma unroll
    for (int mt = 0; mt < 4; mt++)
#pragma unroll
        for (int nt = 0; nt < 4; nt++) acc[mt][nt] = (floatx4){0.f, 0.f, 0.f, 0.f};

#pragma unroll
    for (int ks = 0; ks < 4; ks++) {
        int k0 = ks * 32 + quad * 8;
        half8 a[4], b[4];
#pragma unroll
        for (int mt = 0; mt < 4; mt++)
            a[mt] = *(const half8*)(&As[wm * 64 + mt * 16 + l16][k0]);
#pragma unroll
        for (int nt = 0; nt < 4; nt++)
            b[nt] = *(const half8*)(&Bs[wn * 64 + nt * 16 + l16][k0]);
#pragma unroll
        for (int mt = 0; mt < 4; mt++)
#pragma unroll
            for (int nt = 0; nt < 4; nt++)
                acc[mt][nt] = __builtin_amdgcn_mfma_f32_16x16x32_f16(a[mt], b[nt], acc[mt][nt], 0, 0, 0);
    }

#pragma unroll
    for (int mt = 0; mt < 4; mt++) {
        int rbase = row0 + wm * 64 + mt * 16 + quad * 4;
#pragma unroll
        for (int reg = 0; reg < 4; reg++) {
            int r = rbase + reg;
            if (r < n) {
                float dv = HALF_OUT ? dinv[r] : 1.f;
#pragma unroll
                for (int nt = 0; nt < 4; nt++) {
                    int cc = col0 + wn * 64 + nt * 16 + l16;
                    float val = fmaxf(acc[mt][nt][reg] + bias[cc], 0.f);
                    if (HALF_OUT)
                        ((_Float16*)outp)[(size_t)r * nout + cc] = (_Float16)(val * dv);
                    else
                        ((float*)outp)[(size_t)r * nout + cc] = val;
                }
            }
        }
    }
}

extern "C" void kernel_launch(void* const* d_in, const int* in_sizes, int n_in,
                              void* d_out, int out_size, void* d_ws, size_t ws_size,
                              hipStream_t stream) {
    const float* x  = (const float*)d_in[0];
    const int*   ei = (const int*)d_in[1];
    const float* W1 = (const float*)d_in[2];
    const float* b1 = (const float*)d_in[3];
    const float* W2 = (const float*)d_in[4];
    const float* b2 = (const float*)d_in[5];
    float* out = (float*)d_out;

    int N = in_sizes[0] / 128;   // 50000
    int E = in_sizes[1] / 2;     // 800000
    const int* src = ei;
    const int* dst = ei + E;
    int NB = (N + BNODES - 1) >> BSHIFT;   // 391 buckets

    char* w = (char*)d_ws;
    size_t off = 0;
    auto alloc = [&](size_t bytes) -> char* {
        char* p = w + off;
        off = (off + bytes + 255) & ~(size_t)255;
        return p;
    };
    int*      bucket_fill = (int*)alloc((size_t)NB * 4);
    unsigned* bucketed    = (unsigned*)alloc((size_t)NB * BCAP * 4);
    int*      rowstart    = (int*)alloc((size_t)N * 4);
    int*      rowend      = (int*)alloc((size_t)N * 4);
    float*    dinv        = (float*)alloc((size_t)N * 4);
    int*      csr         = (int*)alloc((size_t)NB * BCAP * 4);
    _Float16* wt1         = (_Float16*)alloc((size_t)128 * 128 * 2);
    _Float16* wt2         = (_Float16*)alloc((size_t)256 * 128 * 2);
    _Float16* xs          = (_Float16*)alloc((size_t)N * 128 * 2);
    _Float16* q1          = (_Float16*)alloc((size_t)N * 128 * 2);
    _Float16* p2          = (_Float16*)alloc((size_t)N * 128 * 2);
    _Float16* q2          = (_Float16*)alloc((size_t)N * 128 * 2);

    int chunk = (E + 255) / 256;          // edges per scatter block
    size_t lds3 = (size_t)NB * 12;        // scatter hist+base+cur

    hipMemsetAsync(bucket_fill, 0, (size_t)NB * 4, stream);
    hipLaunchKernelGGL(scatter_conv_kernel, dim3(256 + 192), dim3(256), lds3, stream,
                       src, dst, bucket_fill, bucketed, W1, W2, wt1, wt2, E, chunk, NB);
    hipLaunchKernelGGL(build_kernel, dim3(NB), dim3(256), 0, stream,
                       bucketed, bucket_fill, x, rowstart, rowend, dinv, csr, xs, N, NB);

    int gbm = (N + 127) / 128;            // 391
    int nwave = (N + 3) / 4;              // one node per quarter-wave
    int nb_agg = (nwave * 64 + 255) / 256;  // 3125 blocks
    // layer 1
    hipLaunchKernelGGL(agg128_kernel, dim3(nb_agg), dim3(256), 0, stream, xs, rowstart, rowend, dinv, csr, q1, N);
    hipLaunchKernelGGL((gemm_kernel<true>), dim3(gbm, 1), dim3(256), 0, stream, q1, wt1, b1, dinv, (void*)p2, N, 128);
    // layer 2
    hipLaunchKernelGGL(agg128_kernel, dim3(nb_agg), dim3(256), 0, stream, p2, rowstart, rowend, dinv, csr, q2, N);
    hipLaunchKernelGGL((gemm_kernel<false>), dim3(gbm, 2), dim3(256), 0, stream, q2, wt2, b2, dinv, (void*)out, N, 256);
}

// Round 7
// 231.201 us; speedup vs baseline: 1.1925x; 1.0625x over previous
//
#include <hip/hip_runtime.h>

// ---------------------------------------------------------------------------
// 2-layer GCN. R16 = R15 with the per-row sort changed from SERIAL INSERTION
// (latency/divergence-bound) to QUARTER-WAVE RANK-SORT (throughput-bound).
// Post-mortems:
//  R10 (212): aggs bound on random line-request service, not instructions.
//  R13 (276): dim-slicing multiplies requests without adding per-XCD reuse.
//  R14 (252): src-sorted rows help aggs -15us (band sweep), but global
//    serial sort cost +55us.
//  R15 (246): LDS-ized insertion sort still 48us: one thread/row, dependent
//    LDS read-compare-write chains (~120cyc each), wave time = max lane
//    (deg~30-40 rows), 391 blocks = no TLP. VALU 3.9%, occ 12% confirm.
// R16: rank-sort. Row -> 16-lane quarter-wave; lane e's rank = count of
// smaller elements (broadcast LDS reads, conflict-free, no dep chains, no
// intra-quarter divergence). Ranks to regs, then in-place write (wave
// lockstep: reads retire before writes; quarters own disjoint rows).
// deg>64 rows left unsorted (P~1e-8, perf-only property).
// Prediction: build 60 -> 15-20us, total ~200-207 (new best). Aggs unchanged
// (csr content identical). If build stays 60, sort model wrong.
// Structure:
//   scatter: packed (src|dst_low7<<16) into fixed per-bucket windows,
//            W fp16-transpose rides on spare blocks.
//   build:   per-bucket LDS degree/scan/fill(LDS)/rank-sort(LDS)/coalesced
//            writeback -> rowstart/rowend/dinv/csr, xs = fp16(x*dinv) fused.
//   q1 = fp16(dinv*(xs_self + sum xs[u]))   [agg128: node-per-quarter]
//   p2 = fp16(relu(q1@W1+b1)*dinv)          [MFMA gemm, fused epilogue]
//   q2 = fp16(dinv*(p2_self + sum p2[u]))   [agg128]
//   out = relu(q2@W2+b2) fp32               [MFMA gemm]
// ---------------------------------------------------------------------------

typedef __attribute__((ext_vector_type(8))) _Float16 half8;
typedef __attribute__((ext_vector_type(4))) _Float16 half4v;
typedef __attribute__((ext_vector_type(4))) float floatx4;

#define BSHIFT 7
#define BNODES 128       // nodes per bucket
#define BCAP   4096      // edge capacity per bucket (mean 2046, sigma ~45)

// ---- scatter packed (src | dst_low7<<16) into fixed bucket windows ---------
// Blocks [0,256): scatter. Blocks [256,448): W1/W2 fp32 -> fp16 transposed.
__global__ __launch_bounds__(256) void scatter_conv_kernel(const int* __restrict__ src,
                                                           const int* __restrict__ dst,
                                                           int* __restrict__ bucket_fill,
                                                           unsigned* __restrict__ bucketed,
                                                           const float* __restrict__ W1,
                                                           const float* __restrict__ W2,
                                                           _Float16* __restrict__ wt1,
                                                           _Float16* __restrict__ wt2,
                                                           int E, int chunk, int NB) {
    int t = threadIdx.x;
    if (blockIdx.x >= 256) {
        int idx = (blockIdx.x - 256) * 256 + t;
        if (idx < 128 * 128) {
            int nn = idx >> 7, k = idx & 127;
            wt1[idx] = (_Float16)W1[k * 128 + nn];
        } else if (idx < (128 + 256) * 128) {
            int j = idx - 128 * 128;
            int nn = j >> 7, k = j & 127;
            wt2[j] = (_Float16)W2[k * 256 + nn];
        }
        return;
    }
    extern __shared__ int sh[];       // hist | base_loc | cur2  (3*NB ints)
    int* hist = sh;
    int* base_loc = sh + NB;
    int* cur2 = sh + 2 * NB;
    for (int i = t; i < NB; i += 256) { hist[i] = 0; cur2[i] = 0; }
    __syncthreads();
    int cbeg = blockIdx.x * chunk;
    int cend = min(E, cbeg + chunk);
    for (int e = cbeg + t; e < cend; e += 256)
        atomicAdd(&hist[dst[e] >> BSHIFT], 1);
    __syncthreads();
    for (int i = t; i < NB; i += 256) {
        int c = hist[i];
        base_loc[i] = c ? atomicAdd(&bucket_fill[i], c) : 0;
    }
    __syncthreads();
    for (int e = cbeg + t; e < cend; e += 256) {
        int d = dst[e];
        int bkt = d >> BSHIFT;
        int r = atomicAdd(&cur2[bkt], 1);
        bucketed[(size_t)bkt * BCAP + base_loc[bkt] + r] =
            (unsigned)src[e] | ((unsigned)(d & (BNODES - 1)) << 16);
    }
}

// ---- per-bucket CSR build (fill + rank-sort in LDS) + dinv + xs ------------
__global__ __launch_bounds__(256) void build_kernel(const unsigned* __restrict__ bucketed,
                                                    const int* __restrict__ bucket_fill,
                                                    const float* __restrict__ x,
                                                    int* __restrict__ rowstart,
                                                    int* __restrict__ rowend,
                                                    float* __restrict__ dinv,
                                                    int* __restrict__ csr,
                                                    _Float16* __restrict__ xs,
                                                    int N, int NB) {
    __shared__ int deg_loc[BNODES];
    __shared__ int tmp[BNODES];
    __shared__ int cur_loc[BNODES];
    __shared__ float dinv_loc[BNODES];
    __shared__ int lcsr[BCAP];        // 16 KB: whole bucket's csr in LDS
    int t = threadIdx.x;
    int b = blockIdx.x;
    int n0 = b << BSHIFT;
    int nodes_in = min(BNODES, N - n0);
    size_t wbase = (size_t)b * BCAP;
    int cnt = bucket_fill[b];

    if (t < BNODES) deg_loc[t] = 0;
    __syncthreads();
    for (int e = t; e < cnt; e += 256)
        atomicAdd(&deg_loc[bucketed[wbase + e] >> 16], 1);
    __syncthreads();
    if (t < BNODES) tmp[t] = deg_loc[t];
    __syncthreads();
    for (int off = 1; off < BNODES; off <<= 1) {
        int v = 0;
        if (t < BNODES && t >= off) v = tmp[t - off];
        __syncthreads();
        if (t < BNODES) tmp[t] += v;
        __syncthreads();
    }
    if (t < BNODES) {
        int loc0 = tmp[t] - deg_loc[t];        // LOCAL (in-bucket) row base
        cur_loc[t] = loc0;
        float dv = rsqrtf((float)(deg_loc[t] + 1));
        dinv_loc[t] = dv;
        if (t < nodes_in) {
            rowstart[n0 + t] = (int)wbase + loc0;
            rowend[n0 + t] = (int)wbase + loc0 + deg_loc[t];
            dinv[n0 + t] = dv;
        }
    }
    __syncthreads();
    // fill rows in LDS (order within row arbitrary; sorted next)
    for (int e = t; e < cnt; e += 256) {
        unsigned u2 = bucketed[wbase + e];
        int pos = atomicAdd(&cur_loc[u2 >> 16], 1);
        lcsr[pos] = (int)(u2 & 0xFFFFu);
    }
    __syncthreads();
    // quarter-wave rank-sort of each row by src (perf-only property: gives
    // the agg sweep its locality band). Lane ql of quarter qw handles
    // elements e = ql, ql+16, ... of each of its rows: rank = count of
    // (smaller) or (equal with lower index). Broadcast LDS reads (16 lanes
    // same address) -> conflict-free, no dependent chains. Ranks to regs,
    // in-place write after (wave lockstep: reads retire before the write
    // instruction; quarters own disjoint rows).
    {
        int qw = t >> 4;        // quarter-wave id 0..15
        int ql = t & 15;        // lane within quarter
        for (int row = qw; row < nodes_in; row += 16) {
            int deg = deg_loc[row];
            if (deg < 2 || deg > 64) continue;   // deg>64: leave unsorted (P~1e-8)
            int rb = tmp[row] - deg;
            int keys[4], ranks[4];
            int ne = 0;
#pragma unroll 4
            for (int e = ql; e < deg; e += 16) {
                int key = lcsr[rb + e];
                int rank = 0;
                for (int j = 0; j < deg; j++) {
                    int v = lcsr[rb + j];
                    rank += (v < key) || (v == key && j < e);
                }
                keys[ne] = key; ranks[ne] = rank; ne++;
            }
            for (int i = 0; i < ne; i++)
                lcsr[rb + ranks[i]] = keys[i];
        }
    }
    __syncthreads();
    // coalesced writeback of the sorted bucket csr
    for (int e = t; e < cnt; e += 256)
        csr[wbase + e] = lcsr[e];
    // xs = fp16(x * dinv) for this bucket's rows (coalesced float4)
    int total4 = nodes_in * 32;  // 32 float4 per 128-wide row
    const float4* x4 = (const float4*)(x + (size_t)n0 * 128);
    for (int i = t; i < total4; i += 256) {
        int row = i >> 5;
        float dv = dinv_loc[row];
        float4 v = x4[i];
        half4v h;
        h[0] = (_Float16)(v.x * dv); h[1] = (_Float16)(v.y * dv);
        h[2] = (_Float16)(v.z * dv); h[3] = (_Float16)(v.w * dv);
        *(half4v*)(xs + (size_t)n0 * 128 + (size_t)i * 4) = h;
    }
}

// ---- 128-dim gather aggregation: ONE NODE PER QUARTER-WAVE -----------------
// q[v] = fp16( dinv[v] * (g[v] + sum_{u->v} g[u]) ); g rows = 256B fp16.
// Edge lists are src-sorted: concurrent waves sweep the table in a compact
// band. 8/4-deep unroll keeps 16-32 gathers in flight per wave.
__global__ __launch_bounds__(256) void agg128_kernel(const _Float16* __restrict__ g,
                                                     const int* __restrict__ rowstart,
                                                     const int* __restrict__ rowend,
                                                     const float* __restrict__ dinv,
                                                     const int* __restrict__ csr,
                                                     _Float16* __restrict__ out, int n) {
    int wave = (blockIdx.x * blockDim.x + threadIdx.x) >> 6;
    int lane = threadIdx.x & 63;
    int q = lane >> 4, l16 = lane & 15;
    int node = wave * 4 + q;
    if (node >= n) return;
    int beg = rowstart[node], end = rowend[node];

    float a[8];
    {   // self term (all lanes active)
        half8 v = *(const half8*)(g + (size_t)node * 128 + l16 * 8);
#pragma unroll
        for (int j = 0; j < 8; j++) a[j] = (float)v[j];
    }
    int e = beg;
    for (; e + 7 < end; e += 8) {   // 8 rows in flight per quarter
        int u0 = csr[e],     u1 = csr[e + 1], u2 = csr[e + 2], u3 = csr[e + 3];
        int u4 = csr[e + 4], u5 = csr[e + 5], u6 = csr[e + 6], u7 = csr[e + 7];
        half8 v0 = *(const half8*)(g + (size_t)u0 * 128 + l16 * 8);
        half8 v1 = *(const half8*)(g + (size_t)u1 * 128 + l16 * 8);
        half8 v2 = *(const half8*)(g + (size_t)u2 * 128 + l16 * 8);
        half8 v3 = *(const half8*)(g + (size_t)u3 * 128 + l16 * 8);
        half8 v4 = *(const half8*)(g + (size_t)u4 * 128 + l16 * 8);
        half8 v5 = *(const half8*)(g + (size_t)u5 * 128 + l16 * 8);
        half8 v6 = *(const half8*)(g + (size_t)u6 * 128 + l16 * 8);
        half8 v7 = *(const half8*)(g + (size_t)u7 * 128 + l16 * 8);
#pragma unroll
        for (int j = 0; j < 8; j++)
            a[j] += (((float)v0[j] + (float)v1[j]) + ((float)v2[j] + (float)v3[j])) +
                    (((float)v4[j] + (float)v5[j]) + ((float)v6[j] + (float)v7[j]));
    }
    for (; e + 3 < end; e += 4) {   // 4 rows in flight
        int u0 = csr[e], u1 = csr[e + 1], u2 = csr[e + 2], u3 = csr[e + 3];
        half8 v0 = *(const half8*)(g + (size_t)u0 * 128 + l16 * 8);
        half8 v1 = *(const half8*)(g + (size_t)u1 * 128 + l16 * 8);
        half8 v2 = *(const half8*)(g + (size_t)u2 * 128 + l16 * 8);
        half8 v3 = *(const half8*)(g + (size_t)u3 * 128 + l16 * 8);
#pragma unroll
        for (int j = 0; j < 8; j++)
            a[j] += ((float)v0[j] + (float)v1[j]) + ((float)v2[j] + (float)v3[j]);
    }
    for (; e < end; e++) {
        int u = csr[e];
        half8 v = *(const half8*)(g + (size_t)u * 128 + l16 * 8);
#pragma unroll
        for (int j = 0; j < 8; j++) a[j] += (float)v[j];
    }
    float dv = dinv[node];
    half8 o;
#pragma unroll
    for (int j = 0; j < 8; j++) o[j] = (_Float16)(a[j] * dv);
    *(half8*)(out + (size_t)node * 128 + l16 * 8) = o;
}

// ---- fp16 MFMA GEMM, K=128, BM=BN=128, fused epilogue ----------------------
// HALF_OUT: out = fp16(relu(acc+bias)*dinv)   else: fp32 relu(acc+bias)
// MFMA layouts (m89/m120): A[m=lane&15][k=(lane>>4)*8+j], B as Bt[n][k],
// D[row=(lane>>4)*4+reg][col=lane&15].
template <bool HALF_OUT>
__global__ __launch_bounds__(256) void gemm_kernel(const _Float16* __restrict__ A,   // [n][128]
                                                   const _Float16* __restrict__ Bt,  // [nout][128]
                                                   const float* __restrict__ bias,
                                                   const float* __restrict__ dinv,
                                                   void* __restrict__ outp,
                                                   int n, int nout) {
    __shared__ _Float16 As[128][136];
    __shared__ _Float16 Bs[128][136];
    int t = threadIdx.x;
    int row0 = blockIdx.x * 128;
    int col0 = blockIdx.y * 128;

#pragma unroll
    for (int i = 0; i < 8; i++) {
        int c = i * 256 + t;
        int r = c >> 4, seg = c & 15;
        int gr = row0 + r;
        if (gr >= n) gr = n - 1;  // clamp; extra rows never stored
        uint4 v = *(const uint4*)(A + (size_t)gr * 128 + seg * 8);
        *(uint4*)(&As[r][seg * 8]) = v;
    }
#pragma unroll
    for (int i = 0; i < 8; i++) {
        int c = i * 256 + t;
        int r = c >> 4, seg = c & 15;
        uint4 v = *(const uint4*)(Bt + (size_t)(col0 + r) * 128 + seg * 8);
        *(uint4*)(&Bs[r][seg * 8]) = v;
    }
    __syncthreads();

    int wid = t >> 6, lane = t & 63;
    int wm = wid >> 1, wn = wid & 1;
    int quad = lane >> 4, l16 = lane & 15;

    floatx4 acc[4][4];
#pragma unroll
    for (int mt = 0; mt < 4; mt++)
#pragma unroll
        for (int nt = 0; nt < 4; nt++) acc[mt][nt] = (floatx4){0.f, 0.f, 0.f, 0.f};

#pragma unroll
    for (int ks = 0; ks < 4; ks++) {
        int k0 = ks * 32 + quad * 8;
        half8 a[4], b[4];
#pragma unroll
        for (int mt = 0; mt < 4; mt++)
            a[mt] = *(const half8*)(&As[wm * 64 + mt * 16 + l16][k0]);
#pragma unroll
        for (int nt = 0; nt < 4; nt++)
            b[nt] = *(const half8*)(&Bs[wn * 64 + nt * 16 + l16][k0]);
#pragma unroll
        for (int mt = 0; mt < 4; mt++)
#pragma unroll
            for (int nt = 0; nt < 4; nt++)
                acc[mt][nt] = __builtin_amdgcn_mfma_f32_16x16x32_f16(a[mt], b[nt], acc[mt][nt], 0, 0, 0);
    }

#pragma unroll
    for (int mt = 0; mt < 4; mt++) {
        int rbase = row0 + wm * 64 + mt * 16 + quad * 4;
#pragma unroll
        for (int reg = 0; reg < 4; reg++) {
            int r = rbase + reg;
            if (r < n) {
                float dv = HALF_OUT ? dinv[r] : 1.f;
#pragma unroll
                for (int nt = 0; nt < 4; nt++) {
                    int cc = col0 + wn * 64 + nt * 16 + l16;
                    float val = fmaxf(acc[mt][nt][reg] + bias[cc], 0.f);
                    if (HALF_OUT)
                        ((_Float16*)outp)[(size_t)r * nout + cc] = (_Float16)(val * dv);
                    else
                        ((float*)outp)[(size_t)r * nout + cc] = val;
                }
            }
        }
    }
}

extern "C" void kernel_launch(void* const* d_in, const int* in_sizes, int n_in,
                              void* d_out, int out_size, void* d_ws, size_t ws_size,
                              hipStream_t stream) {
    const float* x  = (const float*)d_in[0];
    const int*   ei = (const int*)d_in[1];
    const float* W1 = (const float*)d_in[2];
    const float* b1 = (const float*)d_in[3];
    const float* W2 = (const float*)d_in[4];
    const float* b2 = (const float*)d_in[5];
    float* out = (float*)d_out;

    int N = in_sizes[0] / 128;   // 50000
    int E = in_sizes[1] / 2;     // 800000
    const int* src = ei;
    const int* dst = ei + E;
    int NB = (N + BNODES - 1) >> BSHIFT;   // 391 buckets

    char* w = (char*)d_ws;
    size_t off = 0;
    auto alloc = [&](size_t bytes) -> char* {
        char* p = w + off;
        off = (off + bytes + 255) & ~(size_t)255;
        return p;
    };
    int*      bucket_fill = (int*)alloc((size_t)NB * 4);
    unsigned* bucketed    = (unsigned*)alloc((size_t)NB * BCAP * 4);
    int*      rowstart    = (int*)alloc((size_t)N * 4);
    int*      rowend      = (int*)alloc((size_t)N * 4);
    float*    dinv        = (float*)alloc((size_t)N * 4);
    int*      csr         = (int*)alloc((size_t)NB * BCAP * 4);
    _Float16* wt1         = (_Float16*)alloc((size_t)128 * 128 * 2);
    _Float16* wt2         = (_Float16*)alloc((size_t)256 * 128 * 2);
    _Float16* xs          = (_Float16*)alloc((size_t)N * 128 * 2);
    _Float16* q1          = (_Float16*)alloc((size_t)N * 128 * 2);
    _Float16* p2          = (_Float16*)alloc((size_t)N * 128 * 2);
    _Float16* q2          = (_Float16*)alloc((size_t)N * 128 * 2);

    int chunk = (E + 255) / 256;          // edges per scatter block
    size_t lds3 = (size_t)NB * 12;        // scatter hist+base+cur

    hipMemsetAsync(bucket_fill, 0, (size_t)NB * 4, stream);
    hipLaunchKernelGGL(scatter_conv_kernel, dim3(256 + 192), dim3(256), lds3, stream,
                       src, dst, bucket_fill, bucketed, W1, W2, wt1, wt2, E, chunk, NB);
    hipLaunchKernelGGL(build_kernel, dim3(NB), dim3(256), 0, stream,
                       bucketed, bucket_fill, x, rowstart, rowend, dinv, csr, xs, N, NB);

    int gbm = (N + 127) / 128;            // 391
    int nwave = (N + 3) / 4;              // one node per quarter-wave
    int nb_agg = (nwave * 64 + 255) / 256;  // 3125 blocks
    // layer 1
    hipLaunchKernelGGL(agg128_kernel, dim3(nb_agg), dim3(256), 0, stream, xs, rowstart, rowend, dinv, csr, q1, N);
    hipLaunchKernelGGL((gemm_kernel<true>), dim3(gbm, 1), dim3(256), 0, stream, q1, wt1, b1, dinv, (void*)p2, N, 128);
    // layer 2
    hipLaunchKernelGGL(agg128_kernel, dim3(nb_agg), dim3(256), 0, stream, p2, rowstart, rowend, dinv, csr, q2, N);
    hipLaunchKernelGGL((gemm_kernel<false>), dim3(gbm, 2), dim3(256), 0, stream, q2, wt2, b2, dinv, (void*)out, N, 256);
}